// Round 13
// baseline (464.902 us; speedup 1.0000x reference)
//
#include <hip/hip_runtime.h>

#define B_ 16384
#define T_ 80
#define D_ 12
#define H_ 128
#define BT 32            // batch rows per block
#define NTH 512          // 8 waves
#define NBLK (B_ / BT)   // 512

#define NLOG2E -1.4426950408889634f   // -log2(e)
#define TWOLOG2E 2.8853900817779268f  // 2*log2(e)

typedef unsigned short us_t;
typedef unsigned int u32_t;
typedef short bf16x8 __attribute__((ext_vector_type(8)));
typedef float f32x4 __attribute__((ext_vector_type(4)));

// bit-exact RNE (used in pack kernel)
__device__ __forceinline__ us_t f2bf_bit(float f){
  u32_t x = __float_as_uint(f);
  return (us_t)((x + 0x7FFFu + ((x >> 16) & 1u)) >> 16);
}
// 1-instr convert (k_main): v_cvt_pk_bf16_f32, same src both halves -> order-immune
__device__ __forceinline__ us_t f2bf(float f){
  u32_t r;
  asm("v_cvt_pk_bf16_f32 %0, %1, %2" : "=v"(r) : "v"(f), "v"(f));
  return (us_t)r;
}
__device__ __forceinline__ float bf2f(us_t u){
  union { u32_t i; float f; } v; v.i = ((u32_t)u) << 16; return v.f;
}
__device__ __forceinline__ float rcpf(float x){ return __builtin_amdgcn_rcpf(x); }
#if __has_builtin(__builtin_amdgcn_exp2f)
__device__ __forceinline__ float exp2f_(float x){ return __builtin_amdgcn_exp2f(x); }
#else
__device__ __forceinline__ float exp2f_(float x){ return __expf(0.6931471805599453f * x); }
#endif
__device__ __forceinline__ float sigm(float x){ return rcpf(1.f + __expf(-x)); }

// ---------------- K0a: per-step mask denominators ----------------
__global__ void k_denom(const float* __restrict__ masks, float* __restrict__ denomInv) {
  int t = blockIdx.x, tid = threadIdx.x;
  float s = 0.f;
  for (int b = tid; b < B_; b += 256) {
    const float4* p = (const float4*)(masks + ((size_t)b * T_ + t) * D_);
    float4 a = p[0], c = p[1], d = p[2];
    s += a.x + a.y + a.z + a.w + c.x + c.y + c.z + c.w + d.x + d.y + d.z + d.w;
  }
  __shared__ float r[256];
  r[tid] = s; __syncthreads();
  for (int st = 128; st > 0; st >>= 1) { if (tid < st) r[tid] += r[tid + st]; __syncthreads(); }
  if (tid == 0) denomInv[t] = 1.f / (r[0] + 1e-5f);
}

// ---------------- K0b: pack B-fragments (bf16), pre-scaled for exp2 domain ----------------
__global__ void k_pack(const float* __restrict__ W_ih, const float* __restrict__ W_hh,
                       const float* __restrict__ hist_W, const float* __restrict__ td_h_W,
                       const float* __restrict__ b_ih, const float* __restrict__ b_hh,
                       const float* __restrict__ wc_W,
                       us_t* __restrict__ Wb, us_t* __restrict__ histB,
                       us_t* __restrict__ tdhwB, float* __restrict__ bias_pk,
                       us_t* __restrict__ wcB) {
  int idx = blockIdx.x * 256 + threadIdx.x;
  if (idx < 81920) {
    int i = idx & 7, lane = (idx >> 3) & 63, rest = idx >> 9;
    int kc = rest % 5; rest /= 5;
    int g = rest & 3, w = rest >> 2;
    int n = g * 128 + w * 16 + (lane & 15);
    int k = kc * 32 + ((lane >> 4) << 3) + i;
    float v = 0.f;
    if (k < 24) v = W_ih[n * 24 + k];
    else if (k < 152) v = W_hh[n * 128 + (k - 24)];
    float s = (g == 2) ? TWOLOG2E : NLOG2E;
    Wb[idx] = f2bf_bit(v * s);
  } else if (idx < 83968) {
    int e = idx - 81920;
    int i = e & 7, lane = (e >> 3) & 63, kc = e >> 9;
    int col = lane & 15, k = kc * 32 + ((lane >> 4) << 3) + i;
    histB[e] = f2bf_bit(col < 12 ? hist_W[col * 128 + k] : 0.f);
  } else if (idx < 88064) {
    int e = idx - 83968;
    int i = e & 7, lane = (e >> 3) & 63, w = e >> 9;
    int n = w * 16 + (lane & 15), k = ((lane >> 4) << 3) + i;
    tdhwB[e] = f2bf_bit(k < 12 ? td_h_W[n * 12 + k] * NLOG2E : 0.f);
  } else if (idx < 88576) {
    int e = idx - 88064;
    int g = e >> 7;
    float s = (g == 2) ? TWOLOG2E : NLOG2E;
    bias_pk[e] = (b_ih[e] + b_hh[e]) * s;
  } else if (idx < 89088) {
    // wcB: B-frag for alpha = [gx, m] @ wc_W.T  (K=24 pad 32, 12 cols pad 16)
    int e = idx - 88576;
    int i = e & 7, lane = e >> 3;
    int col = lane & 15, k = ((lane >> 4) << 3) + i;
    wcB[e] = f2bf_bit((col < 12 && k < 24) ? wc_W[col * 24 + k] : 0.f);
  }
}

// staging writes from held register float4 (loader threads); BUF = x/m/A destination buffer
// aA_s/dA_s are single-buffered (strict alternation with barriers)
#define STAGE_WRITE(BUF, V) do { \
  if (la == 0) { \
    x_s[BUF][lb][lq*4+0] = (V).x; x_s[BUF][lb][lq*4+1] = (V).y; \
    x_s[BUF][lb][lq*4+2] = (V).z; x_s[BUF][lb][lq*4+3] = (V).w; \
  } else if (la == 1) { \
    m_s[BUF][lb][lq*4+0] = (V).x; m_s[BUF][lb][lq*4+1] = (V).y; \
    m_s[BUF][lb][lq*4+2] = (V).z; m_s[BUF][lb][lq*4+3] = (V).w; \
    float _mv[4] = {(V).x,(V).y,(V).z,(V).w}; \
    _Pragma("unroll") \
    for (int _j = 0; _j < 4; ++_j) { \
      int _k = 12 + lq*4 + _j; \
      us_t _mb = f2bf(_mv[_j]); \
      A_s[BUF][_k>>3][lb][_k&7] = _mb; \
      aA_s[_k>>3][lb][_k&7] = _mb; \
    } \
  } else { \
    float _dv[4] = {(V).x,(V).y,(V).z,(V).w}; \
    _Pragma("unroll") \
    for (int _j = 0; _j < 4; ++_j) { \
      int _i = lq*4+_j; \
      float _gx = exp2f_(fminf(fmaf(_dv[_j], tdxd_s[_i], tdxb_s[_i]), 0.f)); \
      aA_s[_i>>3][lb][_i&7] = f2bf(_gx); \
      dA_s[_i>>3][lb][_i&7] = f2bf(_dv[_j]); \
    } \
  } \
} while(0)

// ---------------- K1: main recurrence (3 barriers/step) ----------------
__global__ __launch_bounds__(NTH) void k_main(
    const float* __restrict__ values, const float* __restrict__ masks, const float* __restrict__ deltas,
    const float* __restrict__ td_h_b, const float* __restrict__ td_x_W, const float* __restrict__ td_x_b,
    const float* __restrict__ hist_b, const float* __restrict__ feat_W, const float* __restrict__ feat_b,
    const float* __restrict__ wc_b,
    const float* __restrict__ out_W, const float* __restrict__ out_b,
    const float* __restrict__ denomInv, const float* __restrict__ bias_pk,
    const us_t* __restrict__ Wb, const us_t* __restrict__ histB, const us_t* __restrict__ tdhwB,
    const us_t* __restrict__ wcB,
    float* __restrict__ blockLoss, float* __restrict__ out_pred, float* __restrict__ out_imp) {

  // A tile in [kgrp][row][8] subtiles: gate-K = {c_c 0..12, m 12..24, h 24..152, pad ..160}
  __shared__ __align__(16) us_t A_s[2][20][BT][8];
  __shared__ __align__(16) us_t dA_s[4][BT][8];    // d(t+1), K pad 32
  __shared__ __align__(16) us_t aA_s[4][BT][8];    // {gx 0..12, m 12..24, pad}
  __shared__ __align__(16) us_t histB_s[4][64][8];
  // stride 13 (coprime with 32 banks): scalar lane reads at fixed k are conflict-free
  __shared__ float x_s[2][BT][13], m_s[2][BT][13];
  __shared__ float cct_s[BT][13], xh_s[BT][13], al_s[BT][13];
  __shared__ float featW_s[12][12];
  __shared__ float featb_s[12], tdxd_s[12], tdxb_s[12];
  __shared__ float outW_s[128];
  __shared__ float denomInv_s[80];
  __shared__ float outb_s;
  __shared__ float red_s[NTH];

  const int tid = threadIdx.x;
  const int bs = blockIdx.x * BT;
  const int w = tid >> 6, l = tid & 63;
  const int lr = l & 15, lg = l >> 4;

  // ---- one-time init ----
  for (int i = tid; i < 144; i += NTH)
    featW_s[i / 12][i % 12] = ((i / 12) == (i % 12)) ? 0.f : feat_W[i];
  if (tid < 12) {
    featb_s[tid] = feat_b[tid];
    tdxd_s[tid] = td_x_W[tid * 12 + tid] * NLOG2E;
    tdxb_s[tid] = td_x_b[tid] * NLOG2E;
  }
  if (tid < 128) outW_s[tid] = out_W[tid];
  if (tid < 80) denomInv_s[tid] = denomInv[tid];
  if (tid == 0) outb_s = out_b[0];
  for (int i = tid; i < 2 * 20 * BT * 8; i += NTH) ((us_t*)A_s)[i] = 0;
  for (int i = tid; i < 4 * BT * 8; i += NTH) { ((us_t*)dA_s)[i] = 0; ((us_t*)aA_s)[i] = 0; }
  for (int i = tid; i < 2048; i += NTH) ((us_t*)histB_s)[i] = histB[i];

  // ---- persistent registers ----
  bf16x8 bq[4][5];
  #pragma unroll
  for (int g = 0; g < 4; ++g)
    #pragma unroll
    for (int kc = 0; kc < 5; ++kc)
      bq[g][kc] = *(const bf16x8*)(Wb + (size_t)((((w * 4 + g) * 5 + kc) * 64 + l) << 3));
  const bf16x8 twf = *(const bf16x8*)(tdhwB + (size_t)(((w * 64) + l) << 3));
  const bf16x8 wcf = *(const bf16x8*)(wcB + (size_t)(l << 3));
  float bjs[4];
  #pragma unroll
  for (int g = 0; g < 4; ++g) bjs[g] = bias_pk[g * 128 + w * 16 + lr];
  const float tdhb_j = td_h_b[w * 16 + lr] * NLOG2E;
  const float hbias = hist_b[lr < 12 ? lr : 0];
  const float wcb_lr = (lr < 12) ? wc_b[lr] : 0.f;

  // loader roles: tid [192,480) -> one float4 of {x,m,d}; 96 per array
  const int lt = tid - 192;
  const bool isLoader = (lt >= 0 && lt < 288);
  const int la = isLoader ? lt / 96 : 0;
  const int lrm = isLoader ? lt % 96 : 0;
  const int lb = lrm / 3, lq = lrm % 3;
  const float* lsrc = (la == 0) ? values : (la == 1) ? masks : deltas;

  float c_st[2][4] = {{0.f,0.f,0.f,0.f},{0.f,0.f,0.f,0.f}};
  float lossAcc = 0.f;
  int cur = 0;
  __syncthreads();

  // ---- prime t=0 staging into buffer 0 (+ aA_s/dA_s for step 0) ----
  if (isLoader) {
    float4 pv = *(const float4*)(lsrc + ((size_t)(bs + lb) * T_) * D_ + lq * 4);
    STAGE_WRITE(0, pv);
  }
  __syncthreads();

  for (int t = 0; t < T_; ++t) {
    const float dInv = denomInv_s[t];
    const int nxt = cur ^ 1;
    float4 ldv;

    // ---- P1: x_h MFMA (w0-1) | alpha MFMA (w2) | t+1 loads | imp store t-1 ----
    if (w < 2) {
      f32x4 xacc = {0.f, 0.f, 0.f, 0.f};
      __builtin_amdgcn_s_setprio(1);
      #pragma unroll
      for (int kc = 0; kc < 4; ++kc) {
        const bf16x8 af = *(const bf16x8*)&A_s[cur][3 + kc * 4 + lg][w * 16 + lr][0];
        const bf16x8 hf = *(const bf16x8*)&histB_s[kc][l][0];
        xacc = __builtin_amdgcn_mfma_f32_16x16x32_bf16(af, hf, xacc, 0, 0, 0);
      }
      __builtin_amdgcn_s_setprio(0);
      if (lr < 12) {
        #pragma unroll
        for (int r = 0; r < 4; ++r) xh_s[w * 16 + lg * 4 + r][lr] = xacc[r] + hbias;
      }
    } else if (w == 2) {
      // alpha = [gx(t), m(t)] @ wc_W.T + wc_b  (aA_s staged during P2 of t-1 / prime)
      f32x4 ac0 = {wcb_lr, wcb_lr, wcb_lr, wcb_lr};
      f32x4 ac1 = ac0;
      __builtin_amdgcn_s_setprio(1);
      const bf16x8 a0 = *(const bf16x8*)&aA_s[lg][lr][0];
      const bf16x8 a1 = *(const bf16x8*)&aA_s[lg][16 + lr][0];
      ac0 = __builtin_amdgcn_mfma_f32_16x16x32_bf16(a0, wcf, ac0, 0, 0, 0);
      ac1 = __builtin_amdgcn_mfma_f32_16x16x32_bf16(a1, wcf, ac1, 0, 0, 0);
      __builtin_amdgcn_s_setprio(0);
      if (lr < 12) {
        #pragma unroll
        for (int r = 0; r < 4; ++r) {
          al_s[lg * 4 + r][lr] = ac0[r];
          al_s[16 + lg * 4 + r][lr] = ac1[r];
        }
      }
    } else if (isLoader) {
      if (t + 1 < T_)
        ldv = *(const float4*)(lsrc + ((size_t)(bs + lb) * T_ + (t + 1)) * D_ + lq * 4);
    } else if (t > 0) {   // tid in [480,512): 32 imp-store threads, 3 quads each
      int ib = tid - 480;
      #pragma unroll
      for (int q = 0; q < 3; ++q) {
        float4 v = make_float4(cct_s[ib][q * 4 + 0], cct_s[ib][q * 4 + 1],
                               cct_s[ib][q * 4 + 2], cct_s[ib][q * 4 + 3]);
        *(float4*)(out_imp + ((size_t)(bs + ib) * T_ + (t - 1)) * D_ + q * 4) = v;
      }
    }
    __syncthreads();

    // ---- P2: stage t+1 || small phase (384 threads) ----
    if (isLoader && (t + 1 < T_)) STAGE_WRITE(nxt, ldv);
    if (tid < 384) {
      int b = tid & 31, i = tid >> 5;
      float xh = xh_s[b][i], xv = x_s[cur][b][i], mv = m_s[cur][b][i];
      float es = fabsf(xv - xh) * mv;
      float zh = featb_s[i];
      #pragma unroll
      for (int k = 0; k < 12; ++k) {
        float xck = fmaf(m_s[cur][b][k], x_s[cur][b][k] - xh_s[b][k], xh_s[b][k]);
        zh = fmaf(xck, featW_s[i][k], zh);
      }
      es += fabsf(xv - zh) * mv;
      float al = al_s[b][i];
      float ch = fmaf(al, zh - xh, xh);
      es += fabsf(xv - ch) * mv;
      lossAcc = fmaf(es, dInv, lossAcc);
      float cc = fmaf(mv, xv - ch, ch);
      cct_s[b][i] = cc;
      A_s[cur][i >> 3][b][i & 7] = f2bf(cc);
    }
    __syncthreads();

    // ---- P3: gate MFMA + gamma MFMA + epilogue (all waves) ----
    {
      f32x4 acc[2][4];
      #pragma unroll
      for (int m = 0; m < 2; ++m)
        #pragma unroll
        for (int g = 0; g < 4; ++g)
          acc[m][g] = (f32x4){bjs[g], bjs[g], bjs[g], bjs[g]};
      __builtin_amdgcn_s_setprio(1);
      #pragma unroll
      for (int kc = 0; kc < 5; ++kc) {
        const bf16x8 a0 = *(const bf16x8*)&A_s[cur][kc * 4 + lg][lr][0];
        const bf16x8 a1 = *(const bf16x8*)&A_s[cur][kc * 4 + lg][16 + lr][0];
        #pragma unroll
        for (int g = 0; g < 4; ++g) {
          acc[0][g] = __builtin_amdgcn_mfma_f32_16x16x32_bf16(a0, bq[g][kc], acc[0][g], 0, 0, 0);
          acc[1][g] = __builtin_amdgcn_mfma_f32_16x16x32_bf16(a1, bq[g][kc], acc[1][g], 0, 0, 0);
        }
      }
      // gamma(t+1) MFMA (dA_s staged during P2 this step), bias-seeded
      f32x4 g0 = {tdhb_j, tdhb_j, tdhb_j, tdhb_j};
      f32x4 g1 = g0;
      const bf16x8 d0 = *(const bf16x8*)&dA_s[lg][lr][0];
      const bf16x8 d1 = *(const bf16x8*)&dA_s[lg][16 + lr][0];
      g0 = __builtin_amdgcn_mfma_f32_16x16x32_bf16(d0, twf, g0, 0, 0, 0);
      g1 = __builtin_amdgcn_mfma_f32_16x16x32_bf16(d1, twf, g1, 0, 0, 0);
      __builtin_amdgcn_s_setprio(0);
      const bool dec = (t + 1 < T_);
      const int kgh = 3 + 2 * w + (lr >> 3), pgh = lr & 7;
      #pragma unroll
      for (int m = 0; m < 2; ++m) {
        #pragma unroll
        for (int r = 0; r < 4; ++r) {
          float gi = rcpf(1.f + exp2f_(acc[m][0][r]));
          float gf = rcpf(1.f + exp2f_(acc[m][1][r]));
          float gg = 1.f - 2.f * rcpf(1.f + exp2f_(acc[m][2][r]));
          float go = rcpf(1.f + exp2f_(acc[m][3][r]));
          float c = fmaf(gf, c_st[m][r], gi * gg);
          c_st[m][r] = c;
          float th = 1.f - 2.f * rcpf(1.f + exp2f_(TWOLOG2E * c));
          float pre = (m == 0 ? g0[r] : g1[r]);
          float gh = dec ? exp2f_(fminf(pre, 0.f)) : 1.f;
          A_s[nxt][kgh][m * 16 + lg * 4 + r][pgh] = f2bf(go * th * gh);
        }
      }
    }
    __syncthreads();
    cur = nxt;
  }

  // ---- final imputation (t = T-1) ----
  if (tid >= 480) {
    int ib = tid - 480;
    #pragma unroll
    for (int q = 0; q < 3; ++q) {
      float4 v = make_float4(cct_s[ib][q * 4 + 0], cct_s[ib][q * 4 + 1],
                             cct_s[ib][q * 4 + 2], cct_s[ib][q * 4 + 3]);
      *(float4*)(out_imp + ((size_t)(bs + ib) * T_ + (T_ - 1)) * D_ + q * 4) = v;
    }
  }

  // ---- predictions (raw final h; no decay at t=T-1) ----
  if (tid < BT) {
    float a = outb_s;
    #pragma unroll 4
    for (int k = 0; k < H_; ++k)
      a = fmaf(bf2f(A_s[cur][3 + (k >> 3)][tid][k & 7]), outW_s[k], a);
    out_pred[bs + tid] = sigm(a);
  }

  // ---- block loss reduce ----
  red_s[tid] = lossAcc;
  __syncthreads();
  for (int s = NTH / 2; s > 0; s >>= 1) { if (tid < s) red_s[tid] += red_s[tid + s]; __syncthreads(); }
  if (tid == 0) blockLoss[blockIdx.x] = red_s[0];
}

// ---------------- K2: final loss (512 partials) ----------------
__global__ void k_final(const float* __restrict__ blockLoss, float* __restrict__ out_loss) {
  __shared__ float r[256];
  int tid = threadIdx.x;
  r[tid] = blockLoss[tid] + blockLoss[tid + 256];
  __syncthreads();
  for (int s = 128; s > 0; s >>= 1) { if (tid < s) r[tid] += r[tid + s]; __syncthreads(); }
  if (tid == 0) out_loss[0] = r[0] * (1.f / (float)T_);
}

extern "C" void kernel_launch(void* const* d_in, const int* in_sizes, int n_in,
                              void* d_out, int out_size, void* d_ws, size_t ws_size,
                              hipStream_t stream) {
  const float* values = (const float*)d_in[0];
  const float* masks  = (const float*)d_in[1];
  const float* deltas = (const float*)d_in[2];
  const float* td_h_W = (const float*)d_in[3];
  const float* td_h_b = (const float*)d_in[4];
  const float* td_x_W = (const float*)d_in[5];
  const float* td_x_b = (const float*)d_in[6];
  const float* hist_W = (const float*)d_in[7];
  const float* hist_b = (const float*)d_in[8];
  const float* feat_W = (const float*)d_in[9];
  const float* feat_b = (const float*)d_in[10];
  const float* wc_W   = (const float*)d_in[11];
  const float* wc_b   = (const float*)d_in[12];
  const float* W_ih   = (const float*)d_in[13];
  const float* b_ih   = (const float*)d_in[14];
  const float* W_hh   = (const float*)d_in[15];
  const float* b_hh   = (const float*)d_in[16];
  const float* out_W  = (const float*)d_in[17];
  const float* out_b  = (const float*)d_in[18];

  float* ws_f      = (float*)d_ws;
  float* denomInv  = ws_f;            // 80 f32
  float* bias_pk   = ws_f + 128;      // 512 f32 (pre-scaled)
  float* blockLoss = ws_f + 1024;     // 512 f32
  us_t* Wb    = (us_t*)(ws_f + 2048); // 81920 bf16 (pre-scaled)
  us_t* histB = Wb + 81920;           // 2048 bf16
  us_t* tdhwB = histB + 2048;         // 4096 bf16 (pre-scaled)
  us_t* wcB   = tdhwB + 4096;         // 512 bf16

  float* out_f = (float*)d_out;       // [loss(1) | predictions(B) | imputations(B*T*D)]

  k_denom<<<T_, 256, 0, stream>>>(masks, denomInv);
  k_pack<<<348, 256, 0, stream>>>(W_ih, W_hh, hist_W, td_h_W, b_ih, b_hh, wc_W,
                                  Wb, histB, tdhwB, bias_pk, wcB);
  k_main<<<NBLK, NTH, 0, stream>>>(values, masks, deltas, td_h_b, td_x_W, td_x_b,
                                   hist_b, feat_W, feat_b, wc_b,
                                   out_W, out_b, denomInv, bias_pk, Wb, histB, tdhwB, wcB,
                                   blockLoss, out_f + 1, out_f + 1 + B_);
  k_final<<<1, 256, 0, stream>>>(blockLoss, out_f);
}

// Round 14
// 448.206 us; speedup vs baseline: 1.0373x; 1.0373x over previous
//
#include <hip/hip_runtime.h>

#define B_ 16384
#define T_ 80
#define D_ 12
#define H_ 128
#define BT 64            // batch rows per block = 2 tiles x 32
#define NTH 512          // 8 waves
#define NBLK (B_ / BT)   // 256

#define NLOG2E -1.4426950408889634f   // -log2(e)
#define TWOLOG2E 2.8853900817779268f  // 2*log2(e)

typedef unsigned short us_t;
typedef unsigned int u32_t;
typedef short bf16x8 __attribute__((ext_vector_type(8)));
typedef float f32x4 __attribute__((ext_vector_type(4)));

// bit-exact RNE (used in pack kernel)
__device__ __forceinline__ us_t f2bf_bit(float f){
  u32_t x = __float_as_uint(f);
  return (us_t)((x + 0x7FFFu + ((x >> 16) & 1u)) >> 16);
}
// 1-instr convert (k_main): v_cvt_pk_bf16_f32, same src both halves -> order-immune
__device__ __forceinline__ us_t f2bf(float f){
  u32_t r;
  asm("v_cvt_pk_bf16_f32 %0, %1, %2" : "=v"(r) : "v"(f), "v"(f));
  return (us_t)r;
}
__device__ __forceinline__ float bf2f(us_t u){
  union { u32_t i; float f; } v; v.i = ((u32_t)u) << 16; return v.f;
}
__device__ __forceinline__ float rcpf(float x){ return __builtin_amdgcn_rcpf(x); }
#if __has_builtin(__builtin_amdgcn_exp2f)
__device__ __forceinline__ float exp2f_(float x){ return __builtin_amdgcn_exp2f(x); }
#else
__device__ __forceinline__ float exp2f_(float x){ return __expf(0.6931471805599453f * x); }
#endif
__device__ __forceinline__ float sigm(float x){ return rcpf(1.f + __expf(-x)); }

// ---------------- K0a: per-step mask denominators ----------------
__global__ void k_denom(const float* __restrict__ masks, float* __restrict__ denomInv) {
  int t = blockIdx.x, tid = threadIdx.x;
  float s = 0.f;
  for (int b = tid; b < B_; b += 256) {
    const float4* p = (const float4*)(masks + ((size_t)b * T_ + t) * D_);
    float4 a = p[0], c = p[1], d = p[2];
    s += a.x + a.y + a.z + a.w + c.x + c.y + c.z + c.w + d.x + d.y + d.z + d.w;
  }
  __shared__ float r[256];
  r[tid] = s; __syncthreads();
  for (int st = 128; st > 0; st >>= 1) { if (tid < st) r[tid] += r[tid + st]; __syncthreads(); }
  if (tid == 0) denomInv[t] = 1.f / (r[0] + 1e-5f);
}

// ---------------- K0b: pack B-fragments (bf16), pre-scaled for exp2 domain ----------------
__global__ void k_pack(const float* __restrict__ W_ih, const float* __restrict__ W_hh,
                       const float* __restrict__ hist_W, const float* __restrict__ td_h_W,
                       const float* __restrict__ b_ih, const float* __restrict__ b_hh,
                       const float* __restrict__ wc_W,
                       us_t* __restrict__ Wb, us_t* __restrict__ histB,
                       us_t* __restrict__ tdhwB, float* __restrict__ bias_pk,
                       us_t* __restrict__ wcB) {
  int idx = blockIdx.x * 256 + threadIdx.x;
  if (idx < 81920) {
    int i = idx & 7, lane = (idx >> 3) & 63, rest = idx >> 9;
    int kc = rest % 5; rest /= 5;
    int g = rest & 3, w = rest >> 2;
    int n = g * 128 + w * 16 + (lane & 15);
    int k = kc * 32 + ((lane >> 4) << 3) + i;
    float v = 0.f;
    if (k < 24) v = W_ih[n * 24 + k];
    else if (k < 152) v = W_hh[n * 128 + (k - 24)];
    float s = (g == 2) ? TWOLOG2E : NLOG2E;
    Wb[idx] = f2bf_bit(v * s);
  } else if (idx < 83968) {
    int e = idx - 81920;
    int i = e & 7, lane = (e >> 3) & 63, kc = e >> 9;
    int col = lane & 15, k = kc * 32 + ((lane >> 4) << 3) + i;
    histB[e] = f2bf_bit(col < 12 ? hist_W[col * 128 + k] : 0.f);
  } else if (idx < 88064) {
    int e = idx - 83968;
    int i = e & 7, lane = (e >> 3) & 63, w = e >> 9;
    int n = w * 16 + (lane & 15), k = ((lane >> 4) << 3) + i;
    tdhwB[e] = f2bf_bit(k < 12 ? td_h_W[n * 12 + k] * NLOG2E : 0.f);
  } else if (idx < 88576) {
    int e = idx - 88064;
    int g = e >> 7;
    float s = (g == 2) ? TWOLOG2E : NLOG2E;
    bias_pk[e] = (b_ih[e] + b_hh[e]) * s;
  } else if (idx < 89088) {
    // wcB: B-frag for alpha = [gx, m] @ wc_W.T  (K=24 pad 32, 12 cols pad 16)
    int e = idx - 88576;
    int i = e & 7, lane = e >> 3;
    int col = lane & 15, k = ((lane >> 4) << 3) + i;
    wcB[e] = f2bf_bit((col < 12 && k < 24) ? wc_W[col * 24 + k] : 0.f);
  }
}

// staging writes from held register float4 (loader threads); TL = tile, BUF = x/m/A dbuf
// aA_s/dA_s are single-buffered per tile (strict alternation with barriers)
#define STAGE_WRITE(TL, BUF, V) do { \
  if (la == 0) { \
    x_s[TL][BUF][lb][lq*4+0] = (V).x; x_s[TL][BUF][lb][lq*4+1] = (V).y; \
    x_s[TL][BUF][lb][lq*4+2] = (V).z; x_s[TL][BUF][lb][lq*4+3] = (V).w; \
  } else if (la == 1) { \
    m_s[TL][BUF][lb][lq*4+0] = (V).x; m_s[TL][BUF][lb][lq*4+1] = (V).y; \
    m_s[TL][BUF][lb][lq*4+2] = (V).z; m_s[TL][BUF][lb][lq*4+3] = (V).w; \
    float _mv[4] = {(V).x,(V).y,(V).z,(V).w}; \
    _Pragma("unroll") \
    for (int _j = 0; _j < 4; ++_j) { \
      int _k = 12 + lq*4 + _j; \
      us_t _mb = f2bf(_mv[_j]); \
      A_s[TL][BUF][_k>>3][lb][_k&7] = _mb; \
      aA_s[TL][_k>>3][lb][_k&7] = _mb; \
    } \
  } else { \
    float _dv[4] = {(V).x,(V).y,(V).z,(V).w}; \
    _Pragma("unroll") \
    for (int _j = 0; _j < 4; ++_j) { \
      int _i = lq*4+_j; \
      float _gx = exp2f_(fminf(fmaf(_dv[_j], tdxd_s[_i], tdxb_s[_i]), 0.f)); \
      aA_s[TL][_i>>3][lb][_i&7] = f2bf(_gx); \
      dA_s[TL][_i>>3][lb][_i&7] = f2bf(_dv[_j]); \
    } \
  } \
} while(0)

// ---------------- K1: main recurrence (2 tiles/block, 3 barriers/step) ----------------
__global__ __launch_bounds__(NTH) void k_main(
    const float* __restrict__ values, const float* __restrict__ masks, const float* __restrict__ deltas,
    const float* __restrict__ td_h_b, const float* __restrict__ td_x_W, const float* __restrict__ td_x_b,
    const float* __restrict__ hist_b, const float* __restrict__ feat_W, const float* __restrict__ feat_b,
    const float* __restrict__ wc_b,
    const float* __restrict__ out_W, const float* __restrict__ out_b,
    const float* __restrict__ denomInv, const float* __restrict__ bias_pk,
    const us_t* __restrict__ Wb, const us_t* __restrict__ histB, const us_t* __restrict__ tdhwB,
    const us_t* __restrict__ wcB,
    float* __restrict__ blockLoss, float* __restrict__ out_pred, float* __restrict__ out_imp) {

  // Per tile: A in [kgrp][row][8] subtiles, gate-K = {c_c 0..12, m 12..24, h 24..152, pad ..160}
  __shared__ __align__(16) us_t A_s[2][2][20][32][8];   // [tile][dbuf] 40 KB
  __shared__ __align__(16) us_t dA_s[2][4][32][8];      // d(t+1) per tile
  __shared__ __align__(16) us_t aA_s[2][4][32][8];      // {gx 0..12, m 12..24} per tile
  __shared__ __align__(16) us_t histB_s[4][64][8];      // shared
  // stride 13 (coprime with 32 banks): scalar lane reads at fixed k are conflict-free
  __shared__ float x_s[2][2][32][13], m_s[2][2][32][13];
  __shared__ float cct_s[2][32][13], xh_s[2][32][13], al_s[2][32][13];
  __shared__ float featW_s[12][12];
  __shared__ float featb_s[12], tdxd_s[12], tdxb_s[12];
  __shared__ float outW_s[128];
  __shared__ float denomInv_s[80];
  __shared__ float outb_s;
  __shared__ float red_s[NTH];

  const int tid = threadIdx.x;
  const int bs = blockIdx.x * BT;           // tile tl starts at bs + tl*32
  const int w = tid >> 6, l = tid & 63;
  const int lr = l & 15, lg = l >> 4;

  // ---- one-time init ----
  for (int i = tid; i < 144; i += NTH)
    featW_s[i / 12][i % 12] = ((i / 12) == (i % 12)) ? 0.f : feat_W[i];
  if (tid < 12) {
    featb_s[tid] = feat_b[tid];
    tdxd_s[tid] = td_x_W[tid * 12 + tid] * NLOG2E;
    tdxb_s[tid] = td_x_b[tid] * NLOG2E;
  }
  if (tid < 128) outW_s[tid] = out_W[tid];
  if (tid < 80) denomInv_s[tid] = denomInv[tid];
  if (tid == 0) outb_s = out_b[0];
  for (int i = tid; i < 2 * 2 * 20 * 32 * 8; i += NTH) ((us_t*)A_s)[i] = 0;
  for (int i = tid; i < 2 * 4 * 32 * 8; i += NTH) { ((us_t*)dA_s)[i] = 0; ((us_t*)aA_s)[i] = 0; }
  for (int i = tid; i < 2048; i += NTH) ((us_t*)histB_s)[i] = histB[i];

  // ---- persistent registers ----
  bf16x8 bq[4][5];
  #pragma unroll
  for (int g = 0; g < 4; ++g)
    #pragma unroll
    for (int kc = 0; kc < 5; ++kc)
      bq[g][kc] = *(const bf16x8*)(Wb + (size_t)((((w * 4 + g) * 5 + kc) * 64 + l) << 3));
  const bf16x8 twf = *(const bf16x8*)(tdhwB + (size_t)(((w * 64) + l) << 3));
  const bf16x8 wcf = *(const bf16x8*)(wcB + (size_t)(l << 3));
  float bjs[4];
  #pragma unroll
  for (int g = 0; g < 4; ++g) bjs[g] = bias_pk[g * 128 + w * 16 + lr];
  const float tdhb_j = td_h_b[w * 16 + lr] * NLOG2E;
  const float hbias = hist_b[lr < 12 ? lr : 0];
  const float wcb_lr = (lr < 12) ? wc_b[lr] : 0.f;

  // loader roles: tid [192,480) -> one float4 of {x,m,d} PER TILE; 96 per array
  const int lt = tid - 192;
  const bool isLoader = (lt >= 0 && lt < 288);
  const int la = isLoader ? lt / 96 : 0;
  const int lrm = isLoader ? lt % 96 : 0;
  const int lb = lrm / 3, lq = lrm % 3;
  const float* lsrc = (la == 0) ? values : (la == 1) ? masks : deltas;

  float c_st[2][2][4];
  #pragma unroll
  for (int tl = 0; tl < 2; ++tl)
    #pragma unroll
    for (int m = 0; m < 2; ++m)
      #pragma unroll
      for (int r = 0; r < 4; ++r) c_st[tl][m][r] = 0.f;
  float lossAcc = 0.f;
  int cur = 0;
  __syncthreads();

  // ---- prime t=0 staging into buffer 0 (+ aA_s/dA_s for step 0), both tiles ----
  if (isLoader) {
    float4 p0 = *(const float4*)(lsrc + ((size_t)(bs + lb) * T_) * D_ + lq * 4);
    float4 p1 = *(const float4*)(lsrc + ((size_t)(bs + 32 + lb) * T_) * D_ + lq * 4);
    STAGE_WRITE(0, 0, p0);
    STAGE_WRITE(1, 0, p1);
  }
  __syncthreads();

  for (int t = 0; t < T_; ++t) {
    const float dInv = denomInv_s[t];
    const int nxt = cur ^ 1;
    float4 ldv0, ldv1;

    // ---- P1: x_h MFMA (w0-1) | alpha MFMA (w2) | t+1 loads | imp store t-1 ----
    if (w < 2) {
      #pragma unroll
      for (int tl = 0; tl < 2; ++tl) {
        f32x4 xacc = {0.f, 0.f, 0.f, 0.f};
        #pragma unroll
        for (int kc = 0; kc < 4; ++kc) {
          const bf16x8 af = *(const bf16x8*)&A_s[tl][cur][3 + kc * 4 + lg][w * 16 + lr][0];
          const bf16x8 hf = *(const bf16x8*)&histB_s[kc][l][0];
          xacc = __builtin_amdgcn_mfma_f32_16x16x32_bf16(af, hf, xacc, 0, 0, 0);
        }
        if (lr < 12) {
          #pragma unroll
          for (int r = 0; r < 4; ++r) xh_s[tl][w * 16 + lg * 4 + r][lr] = xacc[r] + hbias;
        }
      }
    } else if (w == 2) {
      // alpha = [gx(t), m(t)] @ wc_W.T + wc_b  (aA_s staged during P2 of t-1 / prime)
      #pragma unroll
      for (int tl = 0; tl < 2; ++tl) {
        f32x4 ac0 = {wcb_lr, wcb_lr, wcb_lr, wcb_lr};
        f32x4 ac1 = ac0;
        const bf16x8 a0 = *(const bf16x8*)&aA_s[tl][lg][lr][0];
        const bf16x8 a1 = *(const bf16x8*)&aA_s[tl][lg][16 + lr][0];
        ac0 = __builtin_amdgcn_mfma_f32_16x16x32_bf16(a0, wcf, ac0, 0, 0, 0);
        ac1 = __builtin_amdgcn_mfma_f32_16x16x32_bf16(a1, wcf, ac1, 0, 0, 0);
        if (lr < 12) {
          #pragma unroll
          for (int r = 0; r < 4; ++r) {
            al_s[tl][lg * 4 + r][lr] = ac0[r];
            al_s[tl][16 + lg * 4 + r][lr] = ac1[r];
          }
        }
      }
    } else if (isLoader) {
      if (t + 1 < T_) {
        ldv0 = *(const float4*)(lsrc + ((size_t)(bs + lb) * T_ + (t + 1)) * D_ + lq * 4);
        ldv1 = *(const float4*)(lsrc + ((size_t)(bs + 32 + lb) * T_ + (t + 1)) * D_ + lq * 4);
      }
    } else if (t > 0) {   // tid in [480,512): 32 imp-store threads, 3 quads x 2 tiles
      int ib = tid - 480;
      #pragma unroll
      for (int tl = 0; tl < 2; ++tl)
        #pragma unroll
        for (int q = 0; q < 3; ++q) {
          float4 v = make_float4(cct_s[tl][ib][q * 4 + 0], cct_s[tl][ib][q * 4 + 1],
                                 cct_s[tl][ib][q * 4 + 2], cct_s[tl][ib][q * 4 + 3]);
          *(float4*)(out_imp + ((size_t)(bs + tl * 32 + ib) * T_ + (t - 1)) * D_ + q * 4) = v;
        }
    }
    __syncthreads();

    // ---- P2: stage t+1 || small phase (384 threads x 2 tiles) ----
    if (isLoader && (t + 1 < T_)) { STAGE_WRITE(0, nxt, ldv0); STAGE_WRITE(1, nxt, ldv1); }
    if (tid < 384) {
      #pragma unroll
      for (int tl = 0; tl < 2; ++tl) {
        int b = tid & 31, i = tid >> 5;
        float xh = xh_s[tl][b][i], xv = x_s[tl][cur][b][i], mv = m_s[tl][cur][b][i];
        float es = fabsf(xv - xh) * mv;
        float zh = featb_s[i];
        #pragma unroll
        for (int k = 0; k < 12; ++k) {
          float xck = fmaf(m_s[tl][cur][b][k], x_s[tl][cur][b][k] - xh_s[tl][b][k], xh_s[tl][b][k]);
          zh = fmaf(xck, featW_s[i][k], zh);
        }
        es += fabsf(xv - zh) * mv;
        float al = al_s[tl][b][i];
        float ch = fmaf(al, zh - xh, xh);
        es += fabsf(xv - ch) * mv;
        lossAcc = fmaf(es, dInv, lossAcc);
        float cc = fmaf(mv, xv - ch, ch);
        cct_s[tl][b][i] = cc;
        A_s[tl][cur][i >> 3][b][i & 7] = f2bf(cc);
      }
    }
    __syncthreads();

    // ---- P3: per tile: gate MFMA + gamma MFMA + epilogue (all waves; acc reused) ----
    #pragma unroll
    for (int tl = 0; tl < 2; ++tl) {
      f32x4 acc[2][4];
      #pragma unroll
      for (int m = 0; m < 2; ++m)
        #pragma unroll
        for (int g = 0; g < 4; ++g)
          acc[m][g] = (f32x4){bjs[g], bjs[g], bjs[g], bjs[g]};
      __builtin_amdgcn_s_setprio(1);
      #pragma unroll
      for (int kc = 0; kc < 5; ++kc) {
        const bf16x8 a0 = *(const bf16x8*)&A_s[tl][cur][kc * 4 + lg][lr][0];
        const bf16x8 a1 = *(const bf16x8*)&A_s[tl][cur][kc * 4 + lg][16 + lr][0];
        #pragma unroll
        for (int g = 0; g < 4; ++g) {
          acc[0][g] = __builtin_amdgcn_mfma_f32_16x16x32_bf16(a0, bq[g][kc], acc[0][g], 0, 0, 0);
          acc[1][g] = __builtin_amdgcn_mfma_f32_16x16x32_bf16(a1, bq[g][kc], acc[1][g], 0, 0, 0);
        }
      }
      // gamma(t+1) MFMA (dA_s staged during P2 this step), bias-seeded
      f32x4 g0 = {tdhb_j, tdhb_j, tdhb_j, tdhb_j};
      f32x4 g1 = g0;
      const bf16x8 d0 = *(const bf16x8*)&dA_s[tl][lg][lr][0];
      const bf16x8 d1 = *(const bf16x8*)&dA_s[tl][lg][16 + lr][0];
      g0 = __builtin_amdgcn_mfma_f32_16x16x32_bf16(d0, twf, g0, 0, 0, 0);
      g1 = __builtin_amdgcn_mfma_f32_16x16x32_bf16(d1, twf, g1, 0, 0, 0);
      __builtin_amdgcn_s_setprio(0);
      const bool dec = (t + 1 < T_);
      const int kgh = 3 + 2 * w + (lr >> 3), pgh = lr & 7;
      #pragma unroll
      for (int m = 0; m < 2; ++m) {
        #pragma unroll
        for (int r = 0; r < 4; ++r) {
          float gi = rcpf(1.f + exp2f_(acc[m][0][r]));
          float gf = rcpf(1.f + exp2f_(acc[m][1][r]));
          float gg = 1.f - 2.f * rcpf(1.f + exp2f_(acc[m][2][r]));
          float go = rcpf(1.f + exp2f_(acc[m][3][r]));
          float c = fmaf(gf, c_st[tl][m][r], gi * gg);
          c_st[tl][m][r] = c;
          float th = 1.f - 2.f * rcpf(1.f + exp2f_(TWOLOG2E * c));
          float pre = (m == 0 ? g0[r] : g1[r]);
          float gh = dec ? exp2f_(fminf(pre, 0.f)) : 1.f;
          A_s[tl][nxt][kgh][m * 16 + lg * 4 + r][pgh] = f2bf(go * th * gh);
        }
      }
    }
    __syncthreads();
    cur = nxt;
  }

  // ---- final imputation (t = T-1), both tiles ----
  if (tid >= 480) {
    int ib = tid - 480;
    #pragma unroll
    for (int tl = 0; tl < 2; ++tl)
      #pragma unroll
      for (int q = 0; q < 3; ++q) {
        float4 v = make_float4(cct_s[tl][ib][q * 4 + 0], cct_s[tl][ib][q * 4 + 1],
                               cct_s[tl][ib][q * 4 + 2], cct_s[tl][ib][q * 4 + 3]);
        *(float4*)(out_imp + ((size_t)(bs + tl * 32 + ib) * T_ + (T_ - 1)) * D_ + q * 4) = v;
      }
  }

  // ---- predictions (raw final h; no decay at t=T-1) ----
  if (tid < BT) {
    int tl = tid >> 5, b = tid & 31;
    float a = outb_s;
    #pragma unroll 4
    for (int k = 0; k < H_; ++k)
      a = fmaf(bf2f(A_s[tl][cur][3 + (k >> 3)][b][k & 7]), outW_s[k], a);
    out_pred[bs + tl * 32 + b] = sigm(a);
  }

  // ---- block loss reduce ----
  red_s[tid] = lossAcc;
  __syncthreads();
  for (int s = NTH / 2; s > 0; s >>= 1) { if (tid < s) red_s[tid] += red_s[tid + s]; __syncthreads(); }
  if (tid == 0) blockLoss[blockIdx.x] = red_s[0];
}

// ---------------- K2: final loss (256 partials) ----------------
__global__ void k_final(const float* __restrict__ blockLoss, float* __restrict__ out_loss) {
  __shared__ float r[256];
  int tid = threadIdx.x;
  r[tid] = blockLoss[tid];
  __syncthreads();
  for (int s = 128; s > 0; s >>= 1) { if (tid < s) r[tid] += r[tid + s]; __syncthreads(); }
  if (tid == 0) out_loss[0] = r[0] * (1.f / (float)T_);
}

extern "C" void kernel_launch(void* const* d_in, const int* in_sizes, int n_in,
                              void* d_out, int out_size, void* d_ws, size_t ws_size,
                              hipStream_t stream) {
  const float* values = (const float*)d_in[0];
  const float* masks  = (const float*)d_in[1];
  const float* deltas = (const float*)d_in[2];
  const float* td_h_W = (const float*)d_in[3];
  const float* td_h_b = (const float*)d_in[4];
  const float* td_x_W = (const float*)d_in[5];
  const float* td_x_b = (const float*)d_in[6];
  const float* hist_W = (const float*)d_in[7];
  const float* hist_b = (const float*)d_in[8];
  const float* feat_W = (const float*)d_in[9];
  const float* feat_b = (const float*)d_in[10];
  const float* wc_W   = (const float*)d_in[11];
  const float* wc_b   = (const float*)d_in[12];
  const float* W_ih   = (const float*)d_in[13];
  const float* b_ih   = (const float*)d_in[14];
  const float* W_hh   = (const float*)d_in[15];
  const float* b_hh   = (const float*)d_in[16];
  const float* out_W  = (const float*)d_in[17];
  const float* out_b  = (const float*)d_in[18];

  float* ws_f      = (float*)d_ws;
  float* denomInv  = ws_f;            // 80 f32
  float* bias_pk   = ws_f + 128;      // 512 f32 (pre-scaled)
  float* blockLoss = ws_f + 1024;     // 256 f32
  us_t* Wb    = (us_t*)(ws_f + 2048); // 81920 bf16 (pre-scaled)
  us_t* histB = Wb + 81920;           // 2048 bf16
  us_t* tdhwB = histB + 2048;         // 4096 bf16 (pre-scaled)
  us_t* wcB   = tdhwB + 4096;         // 512 bf16

  float* out_f = (float*)d_out;       // [loss(1) | predictions(B) | imputations(B*T*D)]

  k_denom<<<T_, 256, 0, stream>>>(masks, denomInv);
  k_pack<<<348, 256, 0, stream>>>(W_ih, W_hh, hist_W, td_h_W, b_ih, b_hh, wc_W,
                                  Wb, histB, tdhwB, bias_pk, wcB);
  k_main<<<NBLK, NTH, 0, stream>>>(values, masks, deltas, td_h_b, td_x_W, td_x_b,
                                   hist_b, feat_W, feat_b, wc_b,
                                   out_W, out_b, denomInv, bias_pk, Wb, histB, tdhwB, wcB,
                                   blockLoss, out_f + 1, out_f + 1 + B_);
  k_final<<<1, 256, 0, stream>>>(blockLoss, out_f);
}